// Round 1
// baseline (4043.897 us; speedup 1.0000x reference)
//
#include <hip/hip_runtime.h>
#include <math.h>

// ---------------- problem constants ----------------
#define SEQ    1000
#define BATCH  256
#define INDIM  700
#define H1     256
#define H2     256
#define OUTD   20
#define W1COLS 956   // IN + H1
#define W2COLS 512   // H1 + H2

// ---------------- ws layout (float offsets) ----------------
#define OFF_W1FFT  0                         // 700*256 = 179200
#define OFF_W1RT   179200                    // 256*256 = 65536
#define OFF_W2T    244736                    // 512*256 = 131072
#define OFF_WOUTT  375808                    // 256*20  = 5120
#define OFF_PARAMS 380928                    // 1044 (alpha1,rho1,alpha2,rho2,ao)
#define OFF_STATE  381984                    // 256*1600 = 409600
#define OFF_CUR    791584                    // chunk buffer: Tc*256*256
#define STATE_STRIDE 1600

// ------------------------------------------------------------------
// prep: transpose weights, compute decay constants
// ------------------------------------------------------------------
__global__ __launch_bounds__(256) void prep_kernel(
    const float* __restrict__ W1, const float* __restrict__ W2,
    const float* __restrict__ Wout,
    const float* __restrict__ tau_m1, const float* __restrict__ tau_adp1,
    const float* __restrict__ tau_m2, const float* __restrict__ tau_adp2,
    const float* __restrict__ tau_out,
    float* __restrict__ ws)
{
    const int total = 179200 + 65536 + 131072 + 5120 + 1044; // 381972
    for (int idx = blockIdx.x * 256 + threadIdx.x; idx < total;
         idx += gridDim.x * 256) {
        if (idx < 179200) {                       // W1ffT[k*256+h] = W1[h][k]
            int k = idx >> 8, h = idx & 255;
            ws[OFF_W1FFT + idx] = W1[h * W1COLS + k];
        } else if (idx < 244736) {                // W1rT[j*256+h] = W1[h][700+j]
            int r = idx - 179200;
            int j = r >> 8, h = r & 255;
            ws[OFF_W1RT + r] = W1[h * W1COLS + 700 + j];
        } else if (idx < 375808) {                // W2T[j*256+h] = W2[h][j]
            int r = idx - 244736;
            int j = r >> 8, h = r & 255;
            ws[OFF_W2T + r] = W2[h * W2COLS + j];
        } else if (idx < 380928) {                // WoutT[j*20+o] = Wout[o][j]
            int r = idx - 375808;
            int j = r / 20, o = r % 20;
            ws[OFF_WOUTT + r] = Wout[o * 256 + j];
        } else {                                  // params
            int r = idx - 380928;                 // 0..1043
            float v = 0.f;
            if (r < 256)       { float q = -1.0f / tau_m1[r];        v = (float)exp((double)q); }
            else if (r < 512)  { float q = -1.0f / tau_adp1[r-256];  v = (float)exp((double)q); }
            else if (r < 768)  { float q = -1.0f / tau_m2[r-512];    v = (float)exp((double)q); }
            else if (r < 1024) { float q = -1.0f / tau_adp2[r-768];  v = (float)exp((double)q); }
            else               { float q = -1.0f / tau_out[r-1024];  v = (float)exp((double)q); }
            ws[OFF_PARAMS + r] = v;
        }
    }
}

// ------------------------------------------------------------------
// gemm_ff: cur[m][h] = sum_k x[m][k] * W1ffT[k][h]   (M x 700) @ (700 x 256)
// tile: 64 rows x 256 cols per workgroup, 256 threads, 4x16 per thread
// ------------------------------------------------------------------
__global__ __launch_bounds__(256) void gemm_ff(
    const float* __restrict__ x, const float* __restrict__ B,
    float* __restrict__ cur)
{
    __shared__ float As[8][64];
    __shared__ float Bs[8][256];
    const int tid = threadIdx.x;
    const int m0  = blockIdx.x * 64;
    const int r0  = (tid >> 4) * 4;       // local rows r0..r0+3
    const int cb  = (tid & 15) * 4;       // col groups cb + 64*j

    float4 acc[4][4];
    #pragma unroll
    for (int i = 0; i < 4; ++i)
        #pragma unroll
        for (int j = 0; j < 4; ++j)
            acc[i][j] = make_float4(0.f, 0.f, 0.f, 0.f);

    const int ar = tid >> 2;              // A load: row
    const int ak = (tid & 3) * 2;         // A load: k pair
    const int bk = tid >> 5;              // B load: k row
    const int bc = (tid & 31) * 8;        // B load: col

    for (int k0 = 0; k0 < INDIM; k0 += 8) {
        #pragma unroll
        for (int i = 0; i < 2; ++i) {
            int k = k0 + ak + i;
            As[ak + i][ar] = (k < INDIM) ? x[(size_t)(m0 + ar) * INDIM + k] : 0.f;
        }
        if (k0 + bk < INDIM) {
            const float4* src = (const float4*)&B[(size_t)(k0 + bk) * 256 + bc];
            *(float4*)&Bs[bk][bc]     = src[0];
            *(float4*)&Bs[bk][bc + 4] = src[1];
        } else {
            *(float4*)&Bs[bk][bc]     = make_float4(0.f,0.f,0.f,0.f);
            *(float4*)&Bs[bk][bc + 4] = make_float4(0.f,0.f,0.f,0.f);
        }
        __syncthreads();
        #pragma unroll
        for (int kk = 0; kk < 8; ++kk) {
            float4 a4 = *(const float4*)&As[kk][r0];
            float av[4] = {a4.x, a4.y, a4.z, a4.w};
            #pragma unroll
            for (int j = 0; j < 4; ++j) {
                float4 b4 = *(const float4*)&Bs[kk][cb + 64 * j];
                #pragma unroll
                for (int i = 0; i < 4; ++i) {
                    acc[i][j].x += av[i] * b4.x;
                    acc[i][j].y += av[i] * b4.y;
                    acc[i][j].z += av[i] * b4.z;
                    acc[i][j].w += av[i] * b4.w;
                }
            }
        }
        __syncthreads();
    }
    #pragma unroll
    for (int i = 0; i < 4; ++i)
        #pragma unroll
        for (int j = 0; j < 4; ++j)
            *(float4*)&cur[(size_t)(m0 + r0 + i) * 256 + cb + 64 * j] = acc[i][j];
}

// ------------------------------------------------------------------
// sequential ALIF kernel — skewed pipeline version.
//
// Invariant at top of iteration tt:
//   acc1      = ff(tt) + W1r-gather over z1_{tt-1}          (ready)
//   act2/n2   = active list of z2_{tt-1}                    (ready)
//   opart[]   = Wout partial sums over z2_{tt-1}            (ready, tt>0)
//
// Phases: A(L1 update+ballot) BAR1 B1(uo finalize) B(act1) BAR2
//         C(combined gather: acc1_next + acc2) D(L2 update+ballot) BAR3
//         E(act2) BAR4 F(Wout partial gather, 4-way wave split)
// 4 barriers/step (was 6); one 16-deep load phase (was three 4-deep).
// ------------------------------------------------------------------
__global__ __launch_bounds__(256) void seq_kernel(
    const float* __restrict__ cur1ff,   // T x 256 x 256 (chunk-local)
    const float* __restrict__ W1rT,     // 256 x 256
    const float* __restrict__ W2T,      // 512 x 256
    const float* __restrict__ WoutT,    // 256 x 20
    const float* __restrict__ P,        // params
    float* __restrict__ state,
    float* __restrict__ out,
    int t0, int T)
{
    const int b = blockIdx.x;
    const int h = threadIdx.x;
    const int lane = h & 63, w = h >> 6;

    __shared__ int act1[256];
    __shared__ int act2[256];
    __shared__ unsigned long long wm1[4];
    __shared__ unsigned long long wm2[4];
    __shared__ float opart[128];        // 4 waves x 32 slots (20 used)

    float* st = state + (size_t)b * STATE_STRIDE;

    const float al1 = P[h],        rho1 = P[256 + h];
    const float al2 = P[512 + h],  rho2 = P[768 + h];
    const float om_al1  = __fsub_rn(1.0f, al1);
    const float om_rho1 = __fsub_rn(1.0f, rho1);
    const float om_al2  = __fsub_rn(1.0f, al2);
    const float om_rho2 = __fsub_rn(1.0f, rho2);
    float ao = 0.f, om_ao = 0.f;
    if (h < OUTD) { ao = P[1024 + h]; om_ao = __fsub_rn(1.0f, ao); }

    float u1, a1, z1, u2, a2, z2, uo = 0.f;
    if (t0 == 0) {
        u1 = a1 = z1 = u2 = a2 = z2 = 0.f;
    } else {
        u1 = st[h];        a1 = st[256 + h];
        u2 = st[512 + h];  a2 = st[768 + h];
        z1 = st[1024 + h]; z2 = st[1280 + h];
        if (h < OUTD) uo = st[1536 + h];
    }

    // ---- prologue: build both lists from carried state ----
    int n1, n2;
    {
        unsigned long long b1m = __ballot(z1 > 0.5f);
        unsigned long long b2m = __ballot(z2 > 0.5f);
        if (lane == 0) { wm1[w] = b1m; wm2[w] = b2m; }
        __syncthreads();
        unsigned long long q0 = wm1[0], q1 = wm1[1], q2 = wm1[2], q3 = wm1[3];
        unsigned long long r0 = wm2[0], r1 = wm2[1], r2 = wm2[2], r3 = wm2[3];
        int base1 = 0, base2 = 0;
        if (w > 0) { base1 += __popcll(q0); base2 += __popcll(r0); }
        if (w > 1) { base1 += __popcll(q1); base2 += __popcll(r1); }
        if (w > 2) { base1 += __popcll(q2); base2 += __popcll(r2); }
        unsigned long long below = (1ull << lane) - 1ull;
        if (z1 > 0.5f) act1[base1 + __popcll(b1m & below)] = h;
        if (z2 > 0.5f) act2[base2 + __popcll(b2m & below)] = h;
        n1 = __popcll(q0) + __popcll(q1) + __popcll(q2) + __popcll(q3);
        n2 = __popcll(r0) + __popcll(r1) + __popcll(r2) + __popcll(r3);
        __syncthreads();
    }

    // ---- prologue gather: acc1 for local step 0 ----
    float acc1 = cur1ff[((size_t)b << 8) + h];
    {
        int i = 0;
        for (; i + 8 <= n1; i += 8) {
            int j0 = act1[i],   j1 = act1[i+1], j2 = act1[i+2], j3 = act1[i+3];
            int j4 = act1[i+4], j5 = act1[i+5], j6 = act1[i+6], j7 = act1[i+7];
            float v0 = W1rT[(j0<<8)+h], v1 = W1rT[(j1<<8)+h];
            float v2 = W1rT[(j2<<8)+h], v3 = W1rT[(j3<<8)+h];
            float v4 = W1rT[(j4<<8)+h], v5 = W1rT[(j5<<8)+h];
            float v6 = W1rT[(j6<<8)+h], v7 = W1rT[(j7<<8)+h];
            acc1 += (((v0+v1)+(v2+v3)) + ((v4+v5)+(v6+v7)));
        }
        for (; i < n1; ++i) acc1 += W1rT[(act1[i]<<8)+h];
    }

    for (int tt = 0; tt < T; ++tt) {
        // ---- phase A: prefetch next ff; layer1 update; ballot ----
        float ffn = 0.f;
        if (tt + 1 < T)
            ffn = cur1ff[((size_t)(tt + 1) * 256 + b) * 256 + h];

        a1 = __fadd_rn(__fmul_rn(rho1, a1), __fmul_rn(om_rho1, z1));
        float th1 = __fadd_rn(0.01f, __fmul_rn(1.8f, a1));
        u1 = __fsub_rn(__fadd_rn(__fmul_rn(al1, u1), __fmul_rn(om_al1, acc1)),
                       __fmul_rn(z1, th1));
        z1 = (__fsub_rn(u1, th1) > 0.0f) ? 1.0f : 0.0f;
        unsigned long long bm1 = __ballot(z1 > 0.5f);
        if (lane == 0) wm1[w] = bm1;

        __syncthreads();                          // BAR1

        // ---- phase B1: finalize uo for global step (t0+tt-1) ----
        if (tt > 0 && h < OUTD) {
            float s = ((opart[h] + opart[32 + h]) + (opart[64 + h] + opart[96 + h]));
            uo = __fadd_rn(__fmul_rn(ao, uo), __fmul_rn(om_ao, s));
            int tg = t0 + tt - 1;
            if (tg >= 1)
                out[((size_t)(tg - 1) * BATCH + b) * OUTD + h] = uo;
        }

        // ---- phase B: write act1 entries ----
        {
            unsigned long long q0 = wm1[0], q1 = wm1[1], q2 = wm1[2], q3 = wm1[3];
            int base = 0;
            if (w > 0) base += __popcll(q0);
            if (w > 1) base += __popcll(q1);
            if (w > 2) base += __popcll(q2);
            if (z1 > 0.5f)
                act1[base + __popcll(bm1 & ((1ull << lane) - 1ull))] = h;
            n1 = __popcll(q0) + __popcll(q1) + __popcll(q2) + __popcll(q3);
        }
        __syncthreads();                          // BAR2

        // ---- phase C: combined gather (acc1_next and acc2 together) ----
        float acc1n = ffn, acc2 = 0.f;
        {
            int i = 0;
            for (; i + 8 <= n1; i += 8) {
                int j0 = act1[i],   j1 = act1[i+1], j2 = act1[i+2], j3 = act1[i+3];
                int j4 = act1[i+4], j5 = act1[i+5], j6 = act1[i+6], j7 = act1[i+7];
                float r0 = W1rT[(j0<<8)+h], r1 = W1rT[(j1<<8)+h];
                float r2 = W1rT[(j2<<8)+h], r3 = W1rT[(j3<<8)+h];
                float r4 = W1rT[(j4<<8)+h], r5 = W1rT[(j5<<8)+h];
                float r6 = W1rT[(j6<<8)+h], r7 = W1rT[(j7<<8)+h];
                float s0 = W2T[(j0<<8)+h],  s1 = W2T[(j1<<8)+h];
                float s2 = W2T[(j2<<8)+h],  s3 = W2T[(j3<<8)+h];
                float s4 = W2T[(j4<<8)+h],  s5 = W2T[(j5<<8)+h];
                float s6 = W2T[(j6<<8)+h],  s7 = W2T[(j7<<8)+h];
                acc1n += (((r0+r1)+(r2+r3)) + ((r4+r5)+(r6+r7)));
                acc2  += (((s0+s1)+(s2+s3)) + ((s4+s5)+(s6+s7)));
            }
            if (i + 4 <= n1) {
                int j0 = act1[i], j1 = act1[i+1], j2 = act1[i+2], j3 = act1[i+3];
                float r0 = W1rT[(j0<<8)+h], r1 = W1rT[(j1<<8)+h];
                float r2 = W1rT[(j2<<8)+h], r3 = W1rT[(j3<<8)+h];
                float s0 = W2T[(j0<<8)+h],  s1 = W2T[(j1<<8)+h];
                float s2 = W2T[(j2<<8)+h],  s3 = W2T[(j3<<8)+h];
                acc1n += ((r0+r1)+(r2+r3));
                acc2  += ((s0+s1)+(s2+s3));
                i += 4;
            }
            for (; i < n1; ++i) {
                int j = act1[i];
                acc1n += W1rT[(j<<8)+h];
                acc2  += W2T[(j<<8)+h];
            }
            i = 0;
            for (; i + 8 <= n2; i += 8) {
                int j0 = act2[i],   j1 = act2[i+1], j2 = act2[i+2], j3 = act2[i+3];
                int j4 = act2[i+4], j5 = act2[i+5], j6 = act2[i+6], j7 = act2[i+7];
                float s0 = W2T[((256+j0)<<8)+h], s1 = W2T[((256+j1)<<8)+h];
                float s2 = W2T[((256+j2)<<8)+h], s3 = W2T[((256+j3)<<8)+h];
                float s4 = W2T[((256+j4)<<8)+h], s5 = W2T[((256+j5)<<8)+h];
                float s6 = W2T[((256+j6)<<8)+h], s7 = W2T[((256+j7)<<8)+h];
                acc2 += (((s0+s1)+(s2+s3)) + ((s4+s5)+(s6+s7)));
            }
            if (i + 4 <= n2) {
                int j0 = act2[i], j1 = act2[i+1], j2 = act2[i+2], j3 = act2[i+3];
                float s0 = W2T[((256+j0)<<8)+h], s1 = W2T[((256+j1)<<8)+h];
                float s2 = W2T[((256+j2)<<8)+h], s3 = W2T[((256+j3)<<8)+h];
                acc2 += ((s0+s1)+(s2+s3));
                i += 4;
            }
            for (; i < n2; ++i) acc2 += W2T[((256+act2[i])<<8)+h];
        }

        // ---- phase D: layer2 update; ballot ----
        a2 = __fadd_rn(__fmul_rn(rho2, a2), __fmul_rn(om_rho2, z2));
        float th2 = __fadd_rn(0.01f, __fmul_rn(1.8f, a2));
        u2 = __fsub_rn(__fadd_rn(__fmul_rn(al2, u2), __fmul_rn(om_al2, acc2)),
                       __fmul_rn(z2, th2));
        z2 = (__fsub_rn(u2, th2) > 0.0f) ? 1.0f : 0.0f;
        unsigned long long bm2 = __ballot(z2 > 0.5f);
        if (lane == 0) wm2[w] = bm2;

        __syncthreads();                          // BAR3

        // ---- phase E: write act2 entries ----
        {
            unsigned long long q0 = wm2[0], q1 = wm2[1], q2 = wm2[2], q3 = wm2[3];
            int base = 0;
            if (w > 0) base += __popcll(q0);
            if (w > 1) base += __popcll(q1);
            if (w > 2) base += __popcll(q2);
            if (z2 > 0.5f)
                act2[base + __popcll(bm2 & ((1ull << lane) - 1ull))] = h;
            n2 = __popcll(q0) + __popcll(q1) + __popcll(q2) + __popcll(q3);
        }
        __syncthreads();                          // BAR4

        // ---- phase F: Wout partial gather over new act2, 4-way wave split ----
        if (lane < OUTD) {
            float p = 0.f;
            int i = w;
            for (; i + 12 < n2; i += 16) {
                int j0 = act2[i], j1 = act2[i+4], j2 = act2[i+8], j3 = act2[i+12];
                p += ((WoutT[j0*OUTD + lane] + WoutT[j1*OUTD + lane])
                    + (WoutT[j2*OUTD + lane] + WoutT[j3*OUTD + lane]));
            }
            for (; i < n2; i += 4) p += WoutT[act2[i]*OUTD + lane];
            opart[(w << 5) + lane] = p;
        }

        acc1 = acc1n;
    }

    // ---- epilogue: finalize uo for global step (t0+T-1) ----
    __syncthreads();
    if (h < OUTD) {
        float s = ((opart[h] + opart[32 + h]) + (opart[64 + h] + opart[96 + h]));
        uo = __fadd_rn(__fmul_rn(ao, uo), __fmul_rn(om_ao, s));
        int tg = t0 + T - 1;
        if (tg >= 1)
            out[((size_t)(tg - 1) * BATCH + b) * OUTD + h] = uo;
    }

    // persist state for next chunk
    st[h]        = u1;  st[256 + h]  = a1;
    st[512 + h]  = u2;  st[768 + h]  = a2;
    st[1024 + h] = z1;  st[1280 + h] = z2;
    if (h < OUTD) st[1536 + h] = uo;
}

// ------------------------------------------------------------------
extern "C" void kernel_launch(void* const* d_in, const int* in_sizes, int n_in,
                              void* d_out, int out_size, void* d_ws, size_t ws_size,
                              hipStream_t stream)
{
    const float* x        = (const float*)d_in[0];
    const float* W1       = (const float*)d_in[1];
    const float* tau_m1   = (const float*)d_in[2];
    const float* tau_adp1 = (const float*)d_in[3];
    const float* W2       = (const float*)d_in[4];
    const float* tau_m2   = (const float*)d_in[5];
    const float* tau_adp2 = (const float*)d_in[6];
    const float* Wout     = (const float*)d_in[7];
    const float* tau_out  = (const float*)d_in[8];
    float* out = (float*)d_out;
    float* ws  = (float*)d_ws;

    prep_kernel<<<512, 256, 0, stream>>>(W1, W2, Wout, tau_m1, tau_adp1,
                                         tau_m2, tau_adp2, tau_out, ws);

    size_t ws_floats = ws_size / 4;
    size_t cap = (ws_floats > (size_t)OFF_CUR) ? ws_floats - (size_t)OFF_CUR : 0;
    int Tc = (int)((cap / (BATCH * H1) < (size_t)SEQ) ? cap / (BATCH * H1) : (size_t)SEQ);
    if (Tc < 1) return;  // workspace too small — will fail loudly

    int t0 = 0;
    while (t0 < SEQ) {
        int T = (SEQ - t0 < Tc) ? (SEQ - t0) : Tc;
        gemm_ff<<<dim3(T * (BATCH / 64)), 256, 0, stream>>>(
            x + (size_t)t0 * BATCH * INDIM, ws + OFF_W1FFT, ws + OFF_CUR);
        seq_kernel<<<dim3(BATCH), 256, 0, stream>>>(
            ws + OFF_CUR, ws + OFF_W1RT, ws + OFF_W2T, ws + OFF_WOUTT,
            ws + OFF_PARAMS, ws + OFF_STATE, out, t0, T);
        t0 += T;
    }
}